// Round 13
// baseline (124.715 us; speedup 1.0000x reference)
//
#include <hip/hip_runtime.h>
#include <math.h>

// FeatureWeightNet v13 (MI355X / gfx950)  B=2, C=64, H=512, W=640.
// = v12 wave-private barrier-free pipeline + the two missing fences that
//   caused v12's race (machine scheduler hoisted global_load_lds above the
//   ds_reads of the buffer it overwrites):
//   (1) s_waitcnt lgkmcnt(0) + sched_barrier(0) BEFORE every STAGE
//       -> this wave's ds_reads have returned before DMA can land.
//   (2) sched_barrier(0) AFTER every vmcnt wait -> ds_reads stay below it.
// Structure: each wave owns a private dbuf LDS slab (1ch x 12 x 84 f32);
//   16 passes; counted per-wave vmcnt; zero s_barrier in interior path.
//   Block = 64x16 px x 16 ch; LDS 32.3KB -> 4 blocks/CU (16 waves).
// Grid 2560 = 640 tiles x 4 ch-quads, quad-innermost XCD swizzle.
// Head: 8->16->8->1 MLP + sigmoid from gsum[B,8,H,W] (d_ws), acc fallback.

typedef float f4 __attribute__((ext_vector_type(4)));
#define EPSV 1e-5f
#define LWF 84         // slab row width (floats): 64 + 8 halo + pad; 336B row
#define NF4W 252       // per-wave slab 16B chunks = 12*84/4
#define SLABFW 1008    // floats per wave slab

__device__ __forceinline__ void gload_lds16(const float* g, float* l) {
    auto gp = (const __attribute__((address_space(1))) float*)g;
    auto lp = (__attribute__((address_space(3))) float*)l;
    __builtin_amdgcn_global_load_lds(gp, lp, 16, 0, 0);
}

// 1 channel from this wave's slab -> acc (4 px)
__device__ __forceinline__ f4 compute1(
    const float* sl, int ry4, int qx, const f4* wb, const f4* wn)
{
    f4 acc = (f4){0.f, 0.f, 0.f, 0.f};
    #pragma unroll
    for (int r = 0; r < 5; ++r) {            // tap rows dy = {-4,-2,0,2,4}
        const float* lp = sl + ((ry4 + 2 * r) * LWF + qx * 4);
        const f4 a0 = *(const f4*)(lp);
        const f4 a1 = *(const f4*)(lp + 4);
        const f4 a2 = *(const f4*)(lp + 8);
        if ((r & 1) == 0) {                  // wide taps {-4,0,4}
            const int sy = r >> 1;
            acc += wb[sy * 3 + 0] * a0;
            acc += wb[sy * 3 + 1] * a1;
            acc += wb[sy * 3 + 2] * a2;
        }
        if (r >= 1 && r <= 3) {              // narrow taps {-2,0,2}
            const int sy = r - 1;
            const f4 m0v = __builtin_shufflevector(a0, a1, 2, 3, 4, 5);
            const f4 m2v = __builtin_shufflevector(a1, a2, 2, 3, 4, 5);
            acc += wn[sy * 3 + 0] * m0v;
            acc += wn[sy * 3 + 1] * a1;
            acc += wn[sy * 3 + 2] * m2v;
        }
    }
    return acc;
}

__global__ __launch_bounds__(256, 2) void fwn_stencil(
    const float* __restrict__ F,    // [B,64,H,W]
    const float* __restrict__ off,  // [B,18,H,W]
    float* __restrict__ accp,       // [B,64,H,W]
    float* __restrict__ gsum,       // [B,8,H,W]
    int H, int W, int wg)
{
    const int HW = H * W;
    __shared__ float lds[4][2][SLABFW];      // 4 waves x dbuf = 32256 B

    // 2560 blocks = 8 XCDs * 320; quarter innermost, then y, then strip.
    const int f = blockIdx.x;
    const int l = (f & 7) * 320 + (f >> 3);
    const int quarter = l & 3;               // 16-ch quad 0..3
    const int by      = (l >> 2) & 31;
    const int strip   = l >> 7;              // 0..19
    const int bx = strip % 10;
    const int b  = strip / 10;

    const int tid  = threadIdx.x;
    const int lane = tid & 63;
    const int wv   = tid >> 6;               // wave 0..3
    const int qx   = tid & 15;
    const int ry   = tid >> 4;               // 0..15
    const int ry4  = ry & 3;                 // row within wave
    const int x0 = bx * 64;
    const int h0 = by * 16;
    const int w = x0 + qx * 4;
    const int h = h0 + ry;
    const int cbase = quarter * 16;

    // ---- 18 per-pixel weight f4s, pre-scaled 0.5, loaded once, pinned ----
    const float* op = off + (size_t)b * 18 * HW + h * W + w;
    f4 wb[9], wn[9];
    #pragma unroll
    for (int s = 0; s < 9; ++s) {
        wb[s] = 0.5f * *(const f4*)(op + (size_t)s * HW);
        wn[s] = 0.5f * *(const f4*)(op + (size_t)(s + 9) * HW);
    }
    #pragma unroll
    for (int s = 0; s < 9; ++s) {
        asm volatile("" : "+v"(wb[s]));
        asm volatile("" : "+v"(wn[s]));
    }

    const float* Fb = F + (size_t)(b * 64 + cbase) * HW;
    float* ab  = accp + (size_t)(b * 64 + cbase) * HW + h * W + w;
    float* gp0 = gsum + (size_t)(b * 8 + quarter * 2) * HW + h * W + w;

    // per-wave slab source offsets (channel-invariant; rows reflected)
    int choff[4];
    #pragma unroll
    for (int p = 0; p < 4; ++p) {
        const int j  = p * 64 + lane;
        const int jj = j < NF4W ? j : NF4W - 1;
        const int row = jj / 21;
        const int c4  = jj - row * 21;
        int gr = h0 + 4 * wv - 4 + row;      // wave-private 12 rows
        if (gr < 0) gr = -gr;
        if (gr >= H) gr = 2 * H - 2 - gr;
        choff[p] = gr * W + (x0 - 4) + c4 * 4;
    }

    f4 gs = (f4){0.f, 0.f, 0.f, 0.f};
    f4 gA = (f4){0.f, 0.f, 0.f, 0.f};

    if (bx >= 1 && bx <= 8) {
        // ========== interior: wave-private async pipeline, no barriers ====
#define STAGE(S, BUF) do {                                                    \
        const float* Fp_ = Fb + (size_t)(S) * HW;                             \
        gload_lds16(Fp_ + choff[0], &lds[wv][BUF][0]);                        \
        gload_lds16(Fp_ + choff[1], &lds[wv][BUF][256]);                      \
        gload_lds16(Fp_ + choff[2], &lds[wv][BUF][512]);                      \
        if (lane < NF4W - 192)                                                \
            gload_lds16(Fp_ + choff[3], &lds[wv][BUF][768]);                  \
        } while (0)

// fence BEFORE a STAGE that overwrites a just-read buffer: this wave's
// ds_reads must have RETURNED (lgkmcnt==0) and nothing may be reordered.
#define PRE_STAGE_FENCE() do {                                                \
        asm volatile("s_waitcnt lgkmcnt(0)" ::: "memory");                    \
        __builtin_amdgcn_sched_barrier(0); } while (0)

// vmcnt wait; pin following ds_reads below it.
#define VMW(N) do {                                                           \
        asm volatile("s_waitcnt vmcnt(" #N ")" ::: "memory");                 \
        __builtin_amdgcn_sched_barrier(0); } while (0)

        STAGE(0, 0);
        STAGE(1, 1);
        // ---- pass 0 (peeled): younger than S0 = S1(4) ----
        VMW(4);
        {
            f4 acc = compute1(&lds[wv][0][0], ry4, qx, wb, wn);
            __builtin_nontemporal_store(acc, (f4*)(ab));
            gs += acc;
            PRE_STAGE_FENCE();
            STAGE(2, 0);
        }
        // ---- passes 1..14: younger than Sk = st(k-1) + S(k+1) = 5 ----
        #pragma unroll 1
        for (int k = 1; k < 15; ++k) {
            VMW(5);
            f4 acc = compute1(&lds[wv][k & 1][0], ry4, qx, wb, wn);
            __builtin_nontemporal_store(acc, (f4*)(ab + (size_t)k * HW));
            gs += acc;
            if (k == 7) { gA = gs; gs = (f4){0.f, 0.f, 0.f, 0.f}; }
            if (k < 14) {
                PRE_STAGE_FENCE();
                STAGE(k + 2, k & 1);
            }
        }
        // ---- pass 15 (peeled): drain remaining loads ----
        VMW(1);
        {
            f4 acc = compute1(&lds[wv][1][0], ry4, qx, wb, wn);
            __builtin_nontemporal_store(acc, (f4*)(ab + (size_t)15 * HW));
            gs += acc;
        }
    } else {
        // ========== border-x: wave-private sync path (reflect-x) =========
        int cref[4][4];
        #pragma unroll
        for (int p = 0; p < 4; ++p) {
            const int j  = p * 64 + lane;
            const int jj = j < NF4W ? j : NF4W - 1;
            const int c4 = jj % 21;
            #pragma unroll
            for (int m = 0; m < 4; ++m) {
                int x = x0 - 4 + c4 * 4 + m;
                if (x < 0) x = -x;
                if (x >= W) x = 2 * W - 2 - x;
                cref[p][m] = x;
            }
        }
        int rref[4];
        #pragma unroll
        for (int p = 0; p < 4; ++p) {
            const int j  = p * 64 + lane;
            const int jj = j < NF4W ? j : NF4W - 1;
            const int row = jj / 21;
            int gr = h0 + 4 * wv - 4 + row;
            if (gr < 0) gr = -gr;
            if (gr >= H) gr = 2 * H - 2 - gr;
            rref[p] = gr * W;
        }
        #pragma unroll 1
        for (int k = 0; k < 16; ++k) {
            const float* Fp = Fb + (size_t)k * HW;
            f4 v[4];
            #pragma unroll
            for (int p = 0; p < 4; ++p) {
                #pragma unroll
                for (int m = 0; m < 4; ++m)
                    v[p][m] = Fp[rref[p] + cref[p][m]];
            }
            #pragma unroll
            for (int p = 0; p < 4; ++p) {
                const int j = p * 64 + lane;
                if (j < NF4W) *(f4*)&lds[wv][0][j * 4] = v[p];
            }
            asm volatile("s_waitcnt lgkmcnt(0)" ::: "memory");
            __builtin_amdgcn_sched_barrier(0);
            f4 acc = compute1(&lds[wv][0][0], ry4, qx, wb, wn);
            __builtin_nontemporal_store(acc, (f4*)(ab + (size_t)k * HW));
            gs += acc;
            if (k == 7) { gA = gs; gs = (f4){0.f, 0.f, 0.f, 0.f}; }
            asm volatile("s_waitcnt lgkmcnt(0)" ::: "memory");
            __builtin_amdgcn_sched_barrier(0);
        }
    }

    if (wg) {
        *(f4*)(gp0)      = gA * 0.125f;
        *(f4*)(gp0 + HW) = gs * 0.125f;
    }
}

__device__ __forceinline__ void mlp4(
    const f4* xs,
    const float* __restrict__ w0, const float* __restrict__ b0,
    const float* __restrict__ g0, const float* __restrict__ beta0,
    const float* __restrict__ m0, const float* __restrict__ v0,
    const float* __restrict__ w1, const float* __restrict__ b1,
    const float* __restrict__ g1, const float* __restrict__ beta1,
    const float* __restrict__ m1, const float* __restrict__ v1,
    const float* __restrict__ ws, const float* __restrict__ bs,
    f4& sv)
{
    #pragma unroll
    for (int p = 0; p < 4; ++p) {
        float y0[16];
        #pragma unroll
        for (int o = 0; o < 16; ++o) {
            const float s0 = g0[o] * rsqrtf(v0[o] + EPSV);
            float z = 0.f;
            #pragma unroll
            for (int i = 0; i < 8; ++i) z += w0[o * 8 + i] * xs[i][p];
            z = z * s0 + (b0[o] - m0[o]) * s0 + beta0[o];
            y0[o] = fmaxf(z, 0.f);
        }
        float y1[8];
        #pragma unroll
        for (int o = 0; o < 8; ++o) {
            const float s1 = g1[o] * rsqrtf(v1[o] + EPSV);
            float z = 0.f;
            #pragma unroll
            for (int i = 0; i < 16; ++i) z += w1[o * 16 + i] * y0[i];
            z = z * s1 + (b1[o] - m1[o]) * s1 + beta1[o];
            y1[o] = fmaxf(z, 0.f);
        }
        float sm = bs[0];
        #pragma unroll
        for (int i = 0; i < 8; ++i) sm += ws[i] * y1[i];
        sv[p] = 1.f / (1.f + __expf(-sm));
    }
}

__global__ __launch_bounds__(256) void fwn_head(
    const float* __restrict__ gsum,
    const float* __restrict__ w0, const float* __restrict__ b0,
    const float* __restrict__ g0, const float* __restrict__ beta0,
    const float* __restrict__ m0, const float* __restrict__ v0,
    const float* __restrict__ w1, const float* __restrict__ b1,
    const float* __restrict__ g1, const float* __restrict__ beta1,
    const float* __restrict__ m1, const float* __restrict__ v1,
    const float* __restrict__ ws, const float* __restrict__ bs,
    float* __restrict__ sig, int HW)
{
    const int jq = blockIdx.x * 256 + threadIdx.x;
    const int qHW = HW >> 2;
    const int b = jq / qHW;
    const int pq = jq - b * qHW;
    const float* gp = gsum + (size_t)b * 8 * HW + pq * 4;
    f4 xs[8];
    #pragma unroll
    for (int g = 0; g < 8; ++g) xs[g] = *(const f4*)(gp + (size_t)g * HW);
    f4 sv;
    mlp4(xs, w0, b0, g0, beta0, m0, v0, w1, b1, g1, beta1, m1, v1, ws, bs, sv);
    *(f4*)(sig + (size_t)b * HW + pq * 4) = sv;
}

__global__ __launch_bounds__(256) void fwn_head_acc(
    const float* __restrict__ accp,
    const float* __restrict__ w0, const float* __restrict__ b0,
    const float* __restrict__ g0, const float* __restrict__ beta0,
    const float* __restrict__ m0, const float* __restrict__ v0,
    const float* __restrict__ w1, const float* __restrict__ b1,
    const float* __restrict__ g1, const float* __restrict__ beta1,
    const float* __restrict__ m1, const float* __restrict__ v1,
    const float* __restrict__ ws, const float* __restrict__ bs,
    float* __restrict__ sig, int HW)
{
    const int jq = blockIdx.x * 256 + threadIdx.x;
    const int qHW = HW >> 2;
    const int b = jq / qHW;
    const int pq = jq - b * qHW;
    const float* ap = accp + (size_t)b * 64 * HW + pq * 4;
    f4 xs[8];
    #pragma unroll
    for (int g = 0; g < 8; ++g) {
        f4 t = (f4){0.f, 0.f, 0.f, 0.f};
        #pragma unroll
        for (int c = 0; c < 8; ++c)
            t += *(const f4*)(ap + (size_t)(g * 8 + c) * HW);
        xs[g] = t * 0.125f;
    }
    f4 sv;
    mlp4(xs, w0, b0, g0, beta0, m0, v0, w1, b1, g1, beta1, m1, v1, ws, bs, sv);
    *(f4*)(sig + (size_t)b * HW + pq * 4) = sv;
}

extern "C" void kernel_launch(void* const* d_in, const int* in_sizes, int n_in,
                              void* d_out, int out_size, void* d_ws, size_t ws_size,
                              hipStream_t stream) {
    const float* F    = (const float*)d_in[0];
    const float* off  = (const float*)d_in[1];
    const float* w0   = (const float*)d_in[2];
    const float* b0   = (const float*)d_in[3];
    const float* g0   = (const float*)d_in[4];
    const float* bt0  = (const float*)d_in[5];
    const float* m0   = (const float*)d_in[6];
    const float* v0   = (const float*)d_in[7];
    const float* w1   = (const float*)d_in[8];
    const float* b1   = (const float*)d_in[9];
    const float* g1   = (const float*)d_in[10];
    const float* bt1  = (const float*)d_in[11];
    const float* m1   = (const float*)d_in[12];
    const float* v1   = (const float*)d_in[13];
    const float* ws   = (const float*)d_in[14];
    const float* bs   = (const float*)d_in[15];

    const int B = 2, H = 512, W = 640;
    const int HW = H * W;
    float* sig  = (float*)d_out;                  // [B,H,W]
    float* accp = sig + (size_t)B * HW;           // [B,64,H,W]
    float* gsum = (float*)d_ws;                   // [B,8,H,W] = 20.97 MB

    const size_t gsum_bytes = (size_t)B * 8 * HW * sizeof(float);
    const int use_ws = (ws_size >= gsum_bytes) ? 1 : 0;
    const int nq = (B * HW) / 4;                  // 163840 -> 640 blocks

    fwn_stencil<<<dim3(2560), dim3(256), 0, stream>>>(
        F, off, accp, gsum, H, W, use_ws);
    if (use_ws) {
        fwn_head<<<dim3(nq / 256), dim3(256), 0, stream>>>(
            gsum, w0, b0, g0, bt0, m0, v0, w1, b1, g1, bt1, m1, v1, ws, bs,
            sig, HW);
    } else {
        fwn_head_acc<<<dim3(nq / 256), dim3(256), 0, stream>>>(
            accp, w0, b0, g0, bt0, m0, v0, w1, b1, g1, bt1, m1, v1, ws, bs,
            sig, HW);
    }
}

// Round 14
// 121.437 us; speedup vs baseline: 1.0270x; 1.0270x over previous
//
#include <hip/hip_runtime.h>
#include <math.h>

// FeatureWeightNet v14 (MI355X / gfx950)  B=2, C=64, H=512, W=640.
// 3-slab rotation, ONE barrier per pass.
//   With 3 buffers + stage-ahead-2, stage(k+2) overwrites buf((k+2)%3) =
//   buf((k-1)%3), which was read in pass k-1; the pre-compute barrier of
//   pass k already certifies every wave finished pass k-1 -> the second
//   (post-compute) barrier of the R9/R11 scheme is redundant. Halves
//   barrier cost vs R11 at equal CPP.
//   CPP=2, slab [2][24][84] f32 = 16.1KB; 3 slabs = 48.4KB -> 3 blocks/CU
//   (12 waves, +50% vs R9's 2 blocks) -- LDS-read overlap is the current
//   bottleneck (2.5GB LDS reads chip-wide ~= 36us floor, ~50% utilized).
//   Counted vmcnt (4/6/2), stage=4 global_load_lds per thread (uniform).
// Grid 2560 = 640 tiles x 4 ch-quads (16 ch), quad-innermost XCD swizzle.
// Head: 8->16->8->1 MLP + sigmoid from gsum[B,8,H,W] (d_ws), acc fallback.

typedef float f4 __attribute__((ext_vector_type(4)));
#define EPSV 1e-5f
#define CPP 2          // channels per pass
#define LWF 84         // slab row width (floats): 64 + 8 halo + 12 pad
#define LHH 24         // slab rows: 16 + 8 halo
#define NF4 1008       // CPP*LHH*LWF/4 16B chunks per slab (4 per thread)
#define SLABF (NF4*4)  // floats per slab

__device__ __forceinline__ void gload_lds16(const float* g, float* l) {
    auto gp = (const __attribute__((address_space(1))) float*)g;
    auto lp = (__attribute__((address_space(3))) float*)l;
    __builtin_amdgcn_global_load_lds(gp, lp, 16, 0, 0);
}

// 2 channels from an LDS slab -> acc[2]
__device__ __forceinline__ void compute2(
    const float* lbuf, int ry, int qx, const f4* wb, const f4* wn, f4* acc)
{
    acc[0] = (f4){0.f, 0.f, 0.f, 0.f};
    acc[1] = (f4){0.f, 0.f, 0.f, 0.f};
    #pragma unroll
    for (int r = 0; r < 5; ++r) {            // tap rows dy = {-4,-2,0,2,4}
        #pragma unroll
        for (int i = 0; i < CPP; ++i) {
            const float* lp = lbuf + ((i * LHH + (ry + 2 * r)) * LWF + qx * 4);
            const f4 a0 = *(const f4*)(lp);
            const f4 a1 = *(const f4*)(lp + 4);
            const f4 a2 = *(const f4*)(lp + 8);
            if ((r & 1) == 0) {              // wide taps {-4,0,4}
                const int sy = r >> 1;
                acc[i] += wb[sy * 3 + 0] * a0;
                acc[i] += wb[sy * 3 + 1] * a1;
                acc[i] += wb[sy * 3 + 2] * a2;
            }
            if (r >= 1 && r <= 3) {          // narrow taps {-2,0,2}
                const int sy = r - 1;
                const f4 m0v = __builtin_shufflevector(a0, a1, 2, 3, 4, 5);
                const f4 m2v = __builtin_shufflevector(a1, a2, 2, 3, 4, 5);
                acc[i] += wn[sy * 3 + 0] * m0v;
                acc[i] += wn[sy * 3 + 1] * a1;
                acc[i] += wn[sy * 3 + 2] * m2v;
            }
        }
    }
}

__global__ __launch_bounds__(256, 3) void fwn_stencil(
    const float* __restrict__ F,    // [B,64,H,W]
    const float* __restrict__ off,  // [B,18,H,W]
    float* __restrict__ accp,       // [B,64,H,W]
    float* __restrict__ gsum,       // [B,8,H,W]
    int H, int W, int wg)
{
    const int HW = H * W;
    __shared__ float lds[3][SLABF];          // 48384 B -> 3 blocks/CU

    // 2560 blocks = 8 XCDs * 320; quarter innermost, then y, then strip.
    const int f = blockIdx.x;
    const int l = (f & 7) * 320 + (f >> 3);
    const int quarter = l & 3;               // 16-ch quad 0..3
    const int by      = (l >> 2) & 31;
    const int strip   = l >> 7;              // 0..19
    const int bx = strip % 10;
    const int b  = strip / 10;

    const int tid = threadIdx.x;
    const int qx = tid & 15;
    const int ry = tid >> 4;                 // 0..15
    const int x0 = bx * 64;
    const int h0 = by * 16;
    const int w = x0 + qx * 4;
    const int h = h0 + ry;
    const int cbase = quarter * 16;

    // ---- 18 per-pixel weight f4s, pre-scaled 0.5, loaded once, pinned ----
    const float* op = off + (size_t)b * 18 * HW + h * W + w;
    f4 wb[9], wn[9];
    #pragma unroll
    for (int s = 0; s < 9; ++s) {
        wb[s] = 0.5f * *(const f4*)(op + (size_t)s * HW);
        wn[s] = 0.5f * *(const f4*)(op + (size_t)(s + 9) * HW);
    }
    #pragma unroll
    for (int s = 0; s < 9; ++s) {
        asm volatile("" : "+v"(wb[s]));
        asm volatile("" : "+v"(wn[s]));
    }

    const float* Fb = F + (size_t)(b * 64 + cbase) * HW;
    float* ab  = accp + (size_t)(b * 64 + cbase) * HW + h * W + w;
    float* gp0 = gsum + (size_t)(b * 8 + quarter * 2) * HW + h * W + w;
    f4 gsr[2];
    gsr[0] = (f4){0.f, 0.f, 0.f, 0.f};
    gsr[1] = (f4){0.f, 0.f, 0.f, 0.f};

    if (bx >= 1 && bx <= 8) {
        // ========= interior: 3-slab rotation, 1 barrier per pass =========
        int choff[4];                        // pass-invariant source offsets
        #pragma unroll
        for (int p = 0; p < 4; ++p) {
            const int j   = p * 256 + tid;
            const int jj  = j < NF4 ? j : NF4 - 1;
            const int ch  = jj / 504;        // 504 = LHH*LWF/4
            const int rem = jj - ch * 504;
            const int row = rem / 21;        // 21 = LWF/4
            const int c4  = rem - row * 21;
            int ar = h0 - 4 + row;
            if (ar < 0) ar = -ar;
            if (ar >= H) ar = 2 * H - 2 - ar;
            choff[p] = ch * HW + ar * W + (x0 - 4) + c4 * 4;
        }

#define STAGE(S, BUF) do {                                                    \
        const float* Fp_ = Fb + (size_t)((S) * CPP) * HW;                     \
        _Pragma("unroll")                                                     \
        for (int p = 0; p < 4; ++p) {                                         \
            if (p * 256 + tid < NF4)                                          \
                gload_lds16(Fp_ + choff[p],                                   \
                            &lds[BUF][(p * 256 + (tid >> 6) * 64) * 4]);      \
        } } while (0)

#define BARRIER() do {                                                        \
        asm volatile("" ::: "memory");                                        \
        __builtin_amdgcn_s_barrier();                                         \
        asm volatile("" ::: "memory"); } while (0)

        // ONE barrier per pass: stage(k+2) -> buf((k+2)%3) == buf((k-1)%3),
        // whose readers (pass k-1) are certified done by THIS pass's barrier.
        // vmcnt: 4 loads/stage, 2 NT stores/pass.
#define PASSI(K, NW) do {                                                     \
        asm volatile("s_waitcnt vmcnt(" #NW ")" ::: "memory");                \
        __builtin_amdgcn_sched_barrier(0);                                    \
        BARRIER();                                                            \
        f4 acc[2];                                                            \
        compute2(&lds[(K) % 3][0], ry, qx, wb, wn, acc);                      \
        __builtin_nontemporal_store(acc[0], (f4*)(ab + (size_t)((K)*2+0)*HW));\
        __builtin_nontemporal_store(acc[1], (f4*)(ab + (size_t)((K)*2+1)*HW));\
        gsr[(K) >> 2] += acc[0] + acc[1];                                     \
        if ((K) + 2 < 8) STAGE((K) + 2, ((K) + 2) % 3);                       \
        } while (0)

        STAGE(0, 0);
        STAGE(1, 1);
        PASSI(0, 4);    // younger than S0: S1(4)
        PASSI(1, 6);    // S2(4) + store0(2)
        PASSI(2, 6);    // S3 + store1
        PASSI(3, 6); PASSI(4, 6); PASSI(5, 6);
        PASSI(6, 6);    // S7(4) + store5(2)
        PASSI(7, 2);    // store6(2)
    } else {
        // ========= border-x: sync reg-gather staging (slab 0) ============
        #pragma unroll 1
        for (int k = 0; k < 8; ++k) {
            const float* Fp = Fb + (size_t)(k * CPP) * HW;
            f4 v[4];
            #pragma unroll
            for (int p = 0; p < 4; ++p) {
                const int j = p * 256 + tid;
                if (j < NF4) {
                    const int ch  = j / 504;
                    const int rem = j - ch * 504;
                    const int row = rem / 21;
                    const int c4  = rem - row * 21;
                    int ar = h0 - 4 + row;
                    if (ar < 0) ar = -ar;
                    if (ar >= H) ar = 2 * H - 2 - ar;
                    const float* src = Fp + (size_t)ch * HW + ar * W;
                    #pragma unroll
                    for (int m = 0; m < 4; ++m) {
                        int x = x0 - 4 + c4 * 4 + m;
                        if (x < 0) x = -x;
                        if (x >= W) x = 2 * W - 2 - x;
                        v[p][m] = src[x];
                    }
                }
            }
            __syncthreads();
            #pragma unroll
            for (int p = 0; p < 4; ++p) {
                const int j = p * 256 + tid;
                if (j < NF4) *(f4*)&lds[0][j * 4] = v[p];
            }
            __syncthreads();
            f4 acc[2];
            compute2(&lds[0][0], ry, qx, wb, wn, acc);
            __builtin_nontemporal_store(acc[0], (f4*)(ab + (size_t)(k*2+0)*HW));
            __builtin_nontemporal_store(acc[1], (f4*)(ab + (size_t)(k*2+1)*HW));
            gsr[k >> 2] += acc[0] + acc[1];
        }
    }

    if (wg) {
        *(f4*)(gp0)      = gsr[0] * 0.125f;
        *(f4*)(gp0 + HW) = gsr[1] * 0.125f;
    }
}

__device__ __forceinline__ void mlp4(
    const f4* xs,
    const float* __restrict__ w0, const float* __restrict__ b0,
    const float* __restrict__ g0, const float* __restrict__ beta0,
    const float* __restrict__ m0, const float* __restrict__ v0,
    const float* __restrict__ w1, const float* __restrict__ b1,
    const float* __restrict__ g1, const float* __restrict__ beta1,
    const float* __restrict__ m1, const float* __restrict__ v1,
    const float* __restrict__ ws, const float* __restrict__ bs,
    f4& sv)
{
    #pragma unroll
    for (int p = 0; p < 4; ++p) {
        float y0[16];
        #pragma unroll
        for (int o = 0; o < 16; ++o) {
            const float s0 = g0[o] * rsqrtf(v0[o] + EPSV);
            float z = 0.f;
            #pragma unroll
            for (int i = 0; i < 8; ++i) z += w0[o * 8 + i] * xs[i][p];
            z = z * s0 + (b0[o] - m0[o]) * s0 + beta0[o];
            y0[o] = fmaxf(z, 0.f);
        }
        float y1[8];
        #pragma unroll
        for (int o = 0; o < 8; ++o) {
            const float s1 = g1[o] * rsqrtf(v1[o] + EPSV);
            float z = 0.f;
            #pragma unroll
            for (int i = 0; i < 16; ++i) z += w1[o * 16 + i] * y0[i];
            z = z * s1 + (b1[o] - m1[o]) * s1 + beta1[o];
            y1[o] = fmaxf(z, 0.f);
        }
        float sm = bs[0];
        #pragma unroll
        for (int i = 0; i < 8; ++i) sm += ws[i] * y1[i];
        sv[p] = 1.f / (1.f + __expf(-sm));
    }
}

__global__ __launch_bounds__(256) void fwn_head(
    const float* __restrict__ gsum,
    const float* __restrict__ w0, const float* __restrict__ b0,
    const float* __restrict__ g0, const float* __restrict__ beta0,
    const float* __restrict__ m0, const float* __restrict__ v0,
    const float* __restrict__ w1, const float* __restrict__ b1,
    const float* __restrict__ g1, const float* __restrict__ beta1,
    const float* __restrict__ m1, const float* __restrict__ v1,
    const float* __restrict__ ws, const float* __restrict__ bs,
    float* __restrict__ sig, int HW)
{
    const int jq = blockIdx.x * 256 + threadIdx.x;
    const int qHW = HW >> 2;
    const int b = jq / qHW;
    const int pq = jq - b * qHW;
    const float* gp = gsum + (size_t)b * 8 * HW + pq * 4;
    f4 xs[8];
    #pragma unroll
    for (int g = 0; g < 8; ++g) xs[g] = *(const f4*)(gp + (size_t)g * HW);
    f4 sv;
    mlp4(xs, w0, b0, g0, beta0, m0, v0, w1, b1, g1, beta1, m1, v1, ws, bs, sv);
    *(f4*)(sig + (size_t)b * HW + pq * 4) = sv;
}

__global__ __launch_bounds__(256) void fwn_head_acc(
    const float* __restrict__ accp,
    const float* __restrict__ w0, const float* __restrict__ b0,
    const float* __restrict__ g0, const float* __restrict__ beta0,
    const float* __restrict__ m0, const float* __restrict__ v0,
    const float* __restrict__ w1, const float* __restrict__ b1,
    const float* __restrict__ g1, const float* __restrict__ beta1,
    const float* __restrict__ m1, const float* __restrict__ v1,
    const float* __restrict__ ws, const float* __restrict__ bs,
    float* __restrict__ sig, int HW)
{
    const int jq = blockIdx.x * 256 + threadIdx.x;
    const int qHW = HW >> 2;
    const int b = jq / qHW;
    const int pq = jq - b * qHW;
    const float* ap = accp + (size_t)b * 64 * HW + pq * 4;
    f4 xs[8];
    #pragma unroll
    for (int g = 0; g < 8; ++g) {
        f4 t = (f4){0.f, 0.f, 0.f, 0.f};
        #pragma unroll
        for (int c = 0; c < 8; ++c)
            t += *(const f4*)(ap + (size_t)(g * 8 + c) * HW);
        xs[g] = t * 0.125f;
    }
    f4 sv;
    mlp4(xs, w0, b0, g0, beta0, m0, v0, w1, b1, g1, beta1, m1, v1, ws, bs, sv);
    *(f4*)(sig + (size_t)b * HW + pq * 4) = sv;
}

extern "C" void kernel_launch(void* const* d_in, const int* in_sizes, int n_in,
                              void* d_out, int out_size, void* d_ws, size_t ws_size,
                              hipStream_t stream) {
    const float* F    = (const float*)d_in[0];
    const float* off  = (const float*)d_in[1];
    const float* w0   = (const float*)d_in[2];
    const float* b0   = (const float*)d_in[3];
    const float* g0   = (const float*)d_in[4];
    const float* bt0  = (const float*)d_in[5];
    const float* m0   = (const float*)d_in[6];
    const float* v0   = (const float*)d_in[7];
    const float* w1   = (const float*)d_in[8];
    const float* b1   = (const float*)d_in[9];
    const float* g1   = (const float*)d_in[10];
    const float* bt1  = (const float*)d_in[11];
    const float* m1   = (const float*)d_in[12];
    const float* v1   = (const float*)d_in[13];
    const float* ws   = (const float*)d_in[14];
    const float* bs   = (const float*)d_in[15];

    const int B = 2, H = 512, W = 640;
    const int HW = H * W;
    float* sig  = (float*)d_out;                  // [B,H,W]
    float* accp = sig + (size_t)B * HW;           // [B,64,H,W]
    float* gsum = (float*)d_ws;                   // [B,8,H,W] = 20.97 MB

    const size_t gsum_bytes = (size_t)B * 8 * HW * sizeof(float);
    const int use_ws = (ws_size >= gsum_bytes) ? 1 : 0;
    const int nq = (B * HW) / 4;                  // 163840 -> 640 blocks

    fwn_stencil<<<dim3(2560), dim3(256), 0, stream>>>(
        F, off, accp, gsum, H, W, use_ws);
    if (use_ws) {
        fwn_head<<<dim3(nq / 256), dim3(256), 0, stream>>>(
            gsum, w0, b0, g0, bt0, m0, v0, w1, b1, g1, bt1, m1, v1, ws, bs,
            sig, HW);
    } else {
        fwn_head_acc<<<dim3(nq / 256), dim3(256), 0, stream>>>(
            accp, w0, b0, g0, bt0, m0, v0, w1, b1, g1, bt1, m1, v1, ws, bs,
            sig, HW);
    }
}